// Round 4
// baseline (352.112 us; speedup 1.0000x reference)
//
#include <hip/hip_runtime.h>
#include <hip/hip_bf16.h>
#include <cstdint>
#include <cstddef>

#define B_ 4
#define S_ 2048
#define E_ 768
#define H_ 12
#define D_ 64

typedef __bf16 bf16x8 __attribute__((ext_vector_type(8)));
typedef float f32x4 __attribute__((ext_vector_type(4)));

__constant__ float c_slopes[12] = {
    0.6299605249f, 0.396850263f, 0.25f, 0.1574901312f,
    0.0992125657f, 0.0625f, 0.0393725328f, 0.0248031414f,
    0.015625f, 0.0098431332f, 0.0062007854f, 0.00390625f};

__device__ __forceinline__ unsigned short f2bf_u(float f) {
    unsigned u = __builtin_bit_cast(unsigned, f);
    u += 0x7fffu + ((u >> 16) & 1u);   // round-to-nearest-even
    return (unsigned short)(u >> 16);
}
__device__ __forceinline__ __bf16 f2bf(float f) {
    unsigned short s = f2bf_u(f);
    return __builtin_bit_cast(__bf16, s);
}

// async global->LDS, 16B per lane, dest = wave-uniform base + lane*16
__device__ __forceinline__ void gload_lds16(const void* g, void* l) {
    __builtin_amdgcn_global_load_lds(
        (const __attribute__((address_space(1))) unsigned int*)g,
        (__attribute__((address_space(3))) unsigned int*)l, 16, 0, 0);
}

// ---------------------------------------------------------------------------
// prep: x fp32 -> bf16 (6.29M elems)
// ---------------------------------------------------------------------------
__global__ __launch_bounds__(256) void cvt_x(const float* __restrict__ src,
                                             __bf16* __restrict__ dst) {
    int i = (blockIdx.x * 256 + threadIdx.x) * 4;
    float4 v = *(const float4*)(src + i);
    ushort4 o;
    o.x = f2bf_u(v.x); o.y = f2bf_u(v.y); o.z = f2bf_u(v.z); o.w = f2bf_u(v.w);
    *(ushort4*)((unsigned short*)dst + i) = o;
}

// ---------------------------------------------------------------------------
// prep: W fp32 [k][n] -> Wt bf16 [n][k]; z picks which of 4 matrices
// ---------------------------------------------------------------------------
__global__ __launch_bounds__(256) void wtrans(const float* __restrict__ W0,
                                              const float* __restrict__ W1,
                                              const float* __restrict__ W2,
                                              const float* __restrict__ W3,
                                              __bf16* __restrict__ Wt) {
    const float* W = blockIdx.z == 0 ? W0 : blockIdx.z == 1 ? W1
                   : blockIdx.z == 2 ? W2 : W3;
    __bf16* out = Wt + (size_t)blockIdx.z * E_ * E_;
    __shared__ alignas(16) __bf16 ts[64 * 72];
    const int t = threadIdx.x;
    const int k0 = blockIdx.y * 64, n0 = blockIdx.x * 64;
#pragma unroll
    for (int i = 0; i < 4; i++) {
        int idx = i * 256 + t;          // 1024 float4 chunks
        int row = idx >> 4, c4 = idx & 15;
        float4 v = *(const float4*)(W + (size_t)(k0 + row) * E_ + n0 + c4 * 4);
        ts[(c4 * 4 + 0) * 72 + row] = f2bf(v.x);
        ts[(c4 * 4 + 1) * 72 + row] = f2bf(v.y);
        ts[(c4 * 4 + 2) * 72 + row] = f2bf(v.z);
        ts[(c4 * 4 + 3) * 72 + row] = f2bf(v.w);
    }
    __syncthreads();
#pragma unroll
    for (int i = 0; i < 2; i++) {
        int idx = i * 256 + t;          // 512 chunks of 8 bf16
        int r = idx >> 3, c8 = idx & 7;
        *(uint4*)((unsigned short*)out + (size_t)(n0 + r) * E_ + k0 + c8 * 8) =
            *(const uint4*)((const unsigned short*)ts + r * 72 + c8 * 8);
    }
}

// ---------------------------------------------------------------------------
// GEMM: out = A(8192x768 bf16) @ Wt^T + bias. Wt is [n][k] bf16.
// R7 single-BK32 m97-style staging (best measured). Bias prefetched into
// registers before the K-loop (scattered 4B loads were latency-exposed in
// the epilogue). z=2 -> V written transposed [bh][d][s].
// ---------------------------------------------------------------------------
template <bool PERM>
__global__ __launch_bounds__(256) void gemm_bf(
    const __bf16* __restrict__ A, const __bf16* __restrict__ WtAll,
    const float* __restrict__ b0, const float* __restrict__ b1,
    const float* __restrict__ b2,
    float* __restrict__ outF, __bf16* __restrict__ outB_base) {
    constexpr int Kd = E_, N = E_;
    __shared__ alignas(16) __bf16 Asm[128 * 32];   // 64B rows, no pad (m97)
    __shared__ alignas(16) __bf16 Bsm[128 * 32];

    const int t = threadIdx.x;
    const int w = t >> 6, lane = t & 63;
    const int qm = lane & 15, quad = lane >> 4;
    const int m0 = blockIdx.y * 128, n0 = blockIdx.x * 128;
    const int wm = (w >> 1) * 64, wn = (w & 1) * 64;
    const int z = blockIdx.z;
    const __bf16* Wt = WtAll + (size_t)z * Kd * N;
    const float* bias = PERM ? (z == 0 ? b0 : z == 1 ? b1 : b2) : b0;
    __bf16* outB = PERM ? outB_base + (size_t)z * ((size_t)B_ * S_ * E_) : nullptr;

    // bias prefetch: 4 scattered loads issued before the K-loop
    float bvv[4];
#pragma unroll
    for (int j = 0; j < 4; j++) bvv[j] = bias[n0 + wn + j * 16 + qm];

    // staging: 1024B wave-chunk = 16 rows x 64B; wave w owns chunks {2w,2w+1}
    const int crow = lane >> 2;       // row within chunk
    const int ccol = lane & 3;        // 16B quarter within row

    f32x4 acc[4][4] = {};

    for (int k0 = 0; k0 < Kd; k0 += 32) {
#pragma unroll
        for (int cc = 0; cc < 2; cc++) {
            int chunk = w * 2 + cc;
            int row = chunk * 16 + crow;
            gload_lds16((const unsigned short*)A + (size_t)(m0 + row) * Kd + k0 + ccol * 8,
                        Asm + chunk * 512);
            gload_lds16((const unsigned short*)Wt + (size_t)(n0 + row) * Kd + k0 + ccol * 8,
                        Bsm + chunk * 512);
        }
        __syncthreads();

        bf16x8 af[4], bg[4];
#pragma unroll
        for (int i = 0; i < 4; i++)
            af[i] = *(const bf16x8*)(Asm + (wm + i * 16 + qm) * 32 + quad * 8);
#pragma unroll
        for (int j = 0; j < 4; j++)
            bg[j] = *(const bf16x8*)(Bsm + (wn + j * 16 + qm) * 32 + quad * 8);
#pragma unroll
        for (int i = 0; i < 4; i++)
#pragma unroll
            for (int j = 0; j < 4; j++)
                acc[i][j] = __builtin_amdgcn_mfma_f32_16x16x32_bf16(
                    af[i], bg[j], acc[i][j], 0, 0, 0);
        __syncthreads();
    }

    // epilogue: C/D layout col=lane&15, row=quad*4+reg
#pragma unroll
    for (int i = 0; i < 4; i++) {
#pragma unroll
        for (int j = 0; j < 4; j++) {
            int col = n0 + wn + j * 16 + qm;
            int rowb = m0 + wm + i * 16 + quad * 4;
            if (PERM && z == 2) {
                // V -> Vt [bh][d][s]: rows r are consecutive s, pack 4 bf16
                int b = rowb >> 11, s = rowb & (S_ - 1);
                int h = col >> 6, d = col & (D_ - 1);
                unsigned short pk4[4];
#pragma unroll
                for (int r = 0; r < 4; r++) pk4[r] = f2bf_u(acc[i][j][r] + bvv[j]);
                uint2 pv;
                pv.x = (unsigned)pk4[0] | ((unsigned)pk4[1] << 16);
                pv.y = (unsigned)pk4[2] | ((unsigned)pk4[3] << 16);
                *(uint2*)((unsigned short*)outB +
                          ((size_t)(b * H_ + h) * D_ + d) * S_ + s) = pv;
            } else {
#pragma unroll
                for (int r = 0; r < 4; r++) {
                    int row = rowb + r;
                    float val = acc[i][j][r] + bvv[j];
                    if (PERM) {
                        int b = row >> 11, s = row & (S_ - 1);
                        int h = col >> 6, d = col & (D_ - 1);
                        outB[(((size_t)(b * H_ + h)) * S_ + s) * D_ + d] = f2bf(val);
                    } else {
                        outF[(size_t)row * N + col] = val;
                    }
                }
            }
        }
    }
}

// ---------------------------------------------------------------------------
// Flash attention (S^T formulation, analytic-max softmax, causal + ALiBi).
// R13 (re-run; previous attempt hit an infra failure, no signal): K/V is
// L2-resident (FETCH_SIZE 32MB = read-once; 6 heads x 0.5MB per XCD < 4MB
// L2 via the 48%8==0 grid mapping), so LDS staging was pure overhead
// (Common-mistake #7 / m169): every iteration paid issue -> vmcnt(0) drain
// -> barrier -> barrier. R12's dbuf attempt failed because the compiler
// can't prove gload_lds writes don't alias the frag ds_reads (drain moved
// before the reads). Instead: read K/V fragments DIRECTLY from global (L2
// hit ~200cyc, 16 independent loads in flight), per-wave P scratch only ->
// ZERO __syncthreads, waves free-run. Frag loads still shared by the H/L
// tile pair (L2 traffic ~600MB, under the 34.5TB/s L2 ceiling).
// s_setprio(1) around MFMA clusters: waves now at different phases = the
// m191-positive regime. LDS 16KB (P only), 3 blocks/CU, paired q-tiles.
// ---------------------------------------------------------------------------
__global__ __launch_bounds__(256, 3) void attn_k(
    const __bf16* __restrict__ Q, const __bf16* __restrict__ K,
    const __bf16* __restrict__ Vt, __bf16* __restrict__ O) {
    __shared__ alignas(16) __bf16 PsmH[4 * 16 * 64];  // per-wave P (H tile)
    __shared__ alignas(16) __bf16 PsmL[4 * 16 * 64];  // per-wave P (L tile)

    const int t = threadIdx.x;
    const int w = t >> 6, lane = t & 63;
    const int qm = lane & 15, quad = lane >> 4;
    const int xp = blockIdx.y;                    // pair id 0..15
    const int qlo = xp, qhi = 31 - xp;            // (xp+1) + (32-xp) = 33 tiles
    const int bh = blockIdx.x;
    const float c2 = c_slopes[bh % H_] * 1.44269504f;     // slope * log2(e)
    const size_t base = (size_t)bh * S_ * D_;

    // Q B-fragments for both tiles (lane qm = q-col, contiguous over d)
    const int bbL = qlo * 64 + w * 16;
    const int bbH = qhi * 64 + w * 16;
    const __bf16* qpL = Q + base + (size_t)(bbL + qm) * D_ + quad * 8;
    const __bf16* qpH = Q + base + (size_t)(bbH + qm) * D_ + quad * 8;
    bf16x8 qL0 = *(const bf16x8*)qpL, qL1 = *(const bf16x8*)(qpL + 32);
    bf16x8 qH0 = *(const bf16x8*)qpH, qH1 = *(const bf16x8*)(qpH + 32);

    f32x4 oaccL[4] = {}, oaccH[4] = {};
    float lsumL = 0.f, lsumH = 0.f;
    char* PbH = (char*)PsmH + w * 2048;           // wave's 16x128B region
    char* PbL = (char*)PsmL + w * 2048;

    // direct-from-L2 fragment base pointers (same per-lane data the swizzled
    // LDS path delivered):
    //   ak[i][h] = K[base + (kt*64+16i+qm)*D + h*32 + quad*8 ..+8]
    //   bv[jd][kh] = Vt[base + (16jd+qm)*S + kt*64 + kh*32 + quad*8 ..+8]
    const __bf16* Kf = K + base + (size_t)qm * D_ + quad * 8;
    const __bf16* Vf = Vt + base + (size_t)qm * S_ + quad * 8;

    // P swizzle: byte bits[6:4] ^= qm&7 within each 128B row
    const int pf = (qm & 7) << 4;

    int kt = 0;  // captured by tile lambda

    bf16x8 ak[4][2], bv[4][2];
    auto tilec = [&](const bf16x8& qf0, const bf16x8& qf1, f32x4* oacc,
                     float& lsum, int bb, char* Pb) {
        // S^T = K Q^T : lane (qm,quad) reg r holds S^T[key=16i+4quad+r][q=qm]
        f32x4 st[4];
        __builtin_amdgcn_s_setprio(1);
#pragma unroll
        for (int i = 0; i < 4; i++) {
            f32x4 zz = {0.f, 0.f, 0.f, 0.f};
            zz = __builtin_amdgcn_mfma_f32_16x16x32_bf16(ak[i][0], qf0, zz, 0, 0, 0);
            zz = __builtin_amdgcn_mfma_f32_16x16x32_bf16(ak[i][1], qf1, zz, 0, 0, 0);
            st[i] = zz;
        }
        __builtin_amdgcn_s_setprio(0);

        // analytic-max softmax: exponent = qk*scale*log2e - c2*key
        const int qi = bb + qm;
        const bool nomask = (kt * 64 + 63) <= bb;
        float ls = 0.f;
        unsigned pk[4][2];
#pragma unroll
        for (int i = 0; i < 4; i++) {
            float bi = -c2 * (float)(kt * 64 + 16 * i + 4 * quad);
            float p[4];
#pragma unroll
            for (int r = 0; r < 4; r++) {
                float tt = st[i][r] * 0.18033688f + (bi - c2 * (float)r);
                float pp = __builtin_amdgcn_exp2f(tt);
                if (!nomask) {
                    int key = kt * 64 + 16 * i + 4 * quad + r;
                    pp = (key > qi) ? 0.f : pp;
                }
                ls += pp;
                p[r] = pp;
            }
            // pack 4 fp32 -> 4 bf16 (round-half-up + v_perm byte select)
            unsigned u0 = __builtin_bit_cast(unsigned, p[0]) + 0x8000u;
            unsigned u1 = __builtin_bit_cast(unsigned, p[1]) + 0x8000u;
            unsigned u2 = __builtin_bit_cast(unsigned, p[2]) + 0x8000u;
            unsigned u3 = __builtin_bit_cast(unsigned, p[3]) + 0x8000u;
            pk[i][0] = __builtin_amdgcn_perm(u1, u0, 0x07060302u);
            pk[i][1] = __builtin_amdgcn_perm(u3, u2, 0x07060302u);
        }
        lsum += ls;

        // P[q=qm][key=16i+4quad+{0..3}] : b64 writes, swizzled within row
#pragma unroll
        for (int i = 0; i < 4; i++) {
            uint2 pv; pv.x = pk[i][0]; pv.y = pk[i][1];
            *(uint2*)(Pb + qm * 128 + ((32 * i + 8 * quad) ^ pf)) = pv;
        }

        // O += P V : A = P rows (b128, swizzled), B = V^T rows
        bf16x8 ap0 = *(const bf16x8*)(Pb + qm * 128 + ((quad * 16) ^ pf));
        bf16x8 ap1 = *(const bf16x8*)(Pb + qm * 128 + ((64 + quad * 16) ^ pf));
        __builtin_amdgcn_s_setprio(1);
#pragma unroll
        for (int jd = 0; jd < 4; jd++) {
            oacc[jd] = __builtin_amdgcn_mfma_f32_16x16x32_bf16(
                ap0, bv[jd][0], oacc[jd], 0, 0, 0);
            oacc[jd] = __builtin_amdgcn_mfma_f32_16x16x32_bf16(
                ap1, bv[jd][1], oacc[jd], 0, 0, 0);
        }
        __builtin_amdgcn_s_setprio(0);
    };

    for (kt = 0; kt <= qhi; kt++) {
        // K A-frags (m=key) and V B-frags (n=d), straight from L2.
        // 16 independent 16B loads; compiler schedules them all before the
        // first dependent MFMA.
#pragma unroll
        for (int i = 0; i < 4; i++) {
            const __bf16* kr = Kf + (size_t)(kt * 64 + 16 * i) * D_;
            ak[i][0] = *(const bf16x8*)(kr);
            ak[i][1] = *(const bf16x8*)(kr + 32);
        }
#pragma unroll
        for (int jd = 0; jd < 4; jd++) {
            const __bf16* vr = Vf + (size_t)(16 * jd) * S_ + kt * 64;
            bv[jd][0] = *(const bf16x8*)(vr);
            bv[jd][1] = *(const bf16x8*)(vr + 32);
        }

        tilec(qH0, qH1, oaccH, lsumH, bbH, PbH);             // always
        if (kt <= qlo) tilec(qL0, qL1, oaccL, lsumL, bbL, PbL);  // uniform branch
    }

    // epilogue: reduce l across quads (lane-local rows), divide, store
    auto epi = [&](f32x4* oacc, float lsum, int bb) {
        float lf = lsum;
        lf += __shfl_xor(lf, 16);
        lf += __shfl_xor(lf, 32);               // full l for q = bb+qm
#pragma unroll
        for (int r = 0; r < 4; r++) {
            float lr = __shfl(lf, 4 * quad + r);  // l for q = bb+4quad+r
            float inv = 1.0f / lr;
            int qrow = bb + 4 * quad + r;
#pragma unroll
            for (int jd = 0; jd < 4; jd++)
                O[base + (size_t)qrow * D_ + 16 * jd + qm] =
                    f2bf(oacc[jd][r] * inv);
        }
    };
    epi(oaccH, lsumH, bbH);
    epi(oaccL, lsumL, bbL);
}

// ---------------------------------------------------------------------------
extern "C" void kernel_launch(void* const* d_in, const int* in_sizes, int n_in,
                              void* d_out, int out_size, void* d_ws, size_t ws_size,
                              hipStream_t stream) {
    (void)in_sizes; (void)n_in; (void)out_size; (void)ws_size;
    const float* x  = (const float*)d_in[0];
    const float* Wq = (const float*)d_in[1];
    const float* bq = (const float*)d_in[2];
    const float* Wk = (const float*)d_in[3];
    const float* bk = (const float*)d_in[4];
    const float* Wv = (const float*)d_in[5];
    const float* bv = (const float*)d_in[6];
    const float* Wo = (const float*)d_in[7];
    const float* bo = (const float*)d_in[8];
    float* out = (float*)d_out;

    const size_t n = (size_t)B_ * H_ * S_ * D_;  // 6291456
    // ws layout (46 MB):
    //  [0,n):   xb (dead after QKV gemm)
    //  [n,2n):  Qb -> Ob (attn reads only its own Q rows before writing them)
    //  [2n,3n): Kb
    //  [3n,4n): Vtb  (V written transposed by QKV gemm epilogue, z=2)
    //  [4n,+):  Wt, 4 x 768*768 bf16
    __bf16* xb  = (__bf16*)d_ws;
    __bf16* Qb  = xb + n;
    __bf16* Kb  = xb + 2 * n;
    __bf16* Vtb = xb + 3 * n;
    __bf16* Wt  = xb + 4 * n;
    __bf16* Ob  = Qb;

    cvt_x<<<6144, 256, 0, stream>>>(x, xb);
    wtrans<<<dim3(12, 12, 4), 256, 0, stream>>>(Wq, Wk, Wv, Wo, Wt);
    gemm_bf<true><<<dim3(6, 64, 3), 256, 0, stream>>>(
        xb, Wt, bq, bk, bv, nullptr, Qb);
    attn_k<<<dim3(48, 16), 256, 0, stream>>>(Qb, Kb, Vtb, Ob);
    gemm_bf<false><<<dim3(6, 64, 1), 256, 0, stream>>>(
        Ob, Wt + 3 * (size_t)E_ * E_, bo, nullptr, nullptr, out, nullptr);
}

// Round 5
// 261.719 us; speedup vs baseline: 1.3454x; 1.3454x over previous
//
#include <hip/hip_runtime.h>
#include <hip/hip_bf16.h>
#include <cstdint>
#include <cstddef>

#define B_ 4
#define S_ 2048
#define E_ 768
#define H_ 12
#define D_ 64

typedef __bf16 bf16x8 __attribute__((ext_vector_type(8)));
typedef float f32x4 __attribute__((ext_vector_type(4)));

__constant__ float c_slopes[12] = {
    0.6299605249f, 0.396850263f, 0.25f, 0.1574901312f,
    0.0992125657f, 0.0625f, 0.0393725328f, 0.0248031414f,
    0.015625f, 0.0098431332f, 0.0062007854f, 0.00390625f};

__device__ __forceinline__ unsigned short f2bf_u(float f) {
    unsigned u = __builtin_bit_cast(unsigned, f);
    u += 0x7fffu + ((u >> 16) & 1u);   // round-to-nearest-even
    return (unsigned short)(u >> 16);
}
__device__ __forceinline__ __bf16 f2bf(float f) {
    unsigned short s = f2bf_u(f);
    return __builtin_bit_cast(__bf16, s);
}

// async global->LDS, 16B per lane, dest = wave-uniform base + lane*16
__device__ __forceinline__ void gload_lds16(const void* g, void* l) {
    __builtin_amdgcn_global_load_lds(
        (const __attribute__((address_space(1))) unsigned int*)g,
        (__attribute__((address_space(3))) unsigned int*)l, 16, 0, 0);
}

// ---------------------------------------------------------------------------
// prep: x fp32 -> bf16 (6.29M elems)
// ---------------------------------------------------------------------------
__global__ __launch_bounds__(256) void cvt_x(const float* __restrict__ src,
                                             __bf16* __restrict__ dst) {
    int i = (blockIdx.x * 256 + threadIdx.x) * 4;
    float4 v = *(const float4*)(src + i);
    ushort4 o;
    o.x = f2bf_u(v.x); o.y = f2bf_u(v.y); o.z = f2bf_u(v.z); o.w = f2bf_u(v.w);
    *(ushort4*)((unsigned short*)dst + i) = o;
}

// ---------------------------------------------------------------------------
// prep: W fp32 [k][n] -> Wt bf16 [n][k]; z picks which of 4 matrices
// ---------------------------------------------------------------------------
__global__ __launch_bounds__(256) void wtrans(const float* __restrict__ W0,
                                              const float* __restrict__ W1,
                                              const float* __restrict__ W2,
                                              const float* __restrict__ W3,
                                              __bf16* __restrict__ Wt) {
    const float* W = blockIdx.z == 0 ? W0 : blockIdx.z == 1 ? W1
                   : blockIdx.z == 2 ? W2 : W3;
    __bf16* out = Wt + (size_t)blockIdx.z * E_ * E_;
    __shared__ alignas(16) __bf16 ts[64 * 72];
    const int t = threadIdx.x;
    const int k0 = blockIdx.y * 64, n0 = blockIdx.x * 64;
#pragma unroll
    for (int i = 0; i < 4; i++) {
        int idx = i * 256 + t;          // 1024 float4 chunks
        int row = idx >> 4, c4 = idx & 15;
        float4 v = *(const float4*)(W + (size_t)(k0 + row) * E_ + n0 + c4 * 4);
        ts[(c4 * 4 + 0) * 72 + row] = f2bf(v.x);
        ts[(c4 * 4 + 1) * 72 + row] = f2bf(v.y);
        ts[(c4 * 4 + 2) * 72 + row] = f2bf(v.z);
        ts[(c4 * 4 + 3) * 72 + row] = f2bf(v.w);
    }
    __syncthreads();
#pragma unroll
    for (int i = 0; i < 2; i++) {
        int idx = i * 256 + t;          // 512 chunks of 8 bf16
        int r = idx >> 3, c8 = idx & 7;
        *(uint4*)((unsigned short*)out + (size_t)(n0 + r) * E_ + k0 + c8 * 8) =
            *(const uint4*)((const unsigned short*)ts + r * 72 + c8 * 8);
    }
}

// ---------------------------------------------------------------------------
// GEMM: out = A(8192x768 bf16) @ Wt^T + bias. Wt is [n][k] bf16.
// R7 single-BK32 m97-style staging (best measured). Bias prefetched into
// registers before the K-loop (scattered 4B loads were latency-exposed in
// the epilogue). z=2 -> V written transposed [bh][d][s].
// ---------------------------------------------------------------------------
template <bool PERM>
__global__ __launch_bounds__(256) void gemm_bf(
    const __bf16* __restrict__ A, const __bf16* __restrict__ WtAll,
    const float* __restrict__ b0, const float* __restrict__ b1,
    const float* __restrict__ b2,
    float* __restrict__ outF, __bf16* __restrict__ outB_base) {
    constexpr int Kd = E_, N = E_;
    __shared__ alignas(16) __bf16 Asm[128 * 32];   // 64B rows, no pad (m97)
    __shared__ alignas(16) __bf16 Bsm[128 * 32];

    const int t = threadIdx.x;
    const int w = t >> 6, lane = t & 63;
    const int qm = lane & 15, quad = lane >> 4;
    const int m0 = blockIdx.y * 128, n0 = blockIdx.x * 128;
    const int wm = (w >> 1) * 64, wn = (w & 1) * 64;
    const int z = blockIdx.z;
    const __bf16* Wt = WtAll + (size_t)z * Kd * N;
    const float* bias = PERM ? (z == 0 ? b0 : z == 1 ? b1 : b2) : b0;
    __bf16* outB = PERM ? outB_base + (size_t)z * ((size_t)B_ * S_ * E_) : nullptr;

    // bias prefetch: 4 scattered loads issued before the K-loop
    float bvv[4];
#pragma unroll
    for (int j = 0; j < 4; j++) bvv[j] = bias[n0 + wn + j * 16 + qm];

    // staging: 1024B wave-chunk = 16 rows x 64B; wave w owns chunks {2w,2w+1}
    const int crow = lane >> 2;       // row within chunk
    const int ccol = lane & 3;        // 16B quarter within row

    f32x4 acc[4][4] = {};

    for (int k0 = 0; k0 < Kd; k0 += 32) {
#pragma unroll
        for (int cc = 0; cc < 2; cc++) {
            int chunk = w * 2 + cc;
            int row = chunk * 16 + crow;
            gload_lds16((const unsigned short*)A + (size_t)(m0 + row) * Kd + k0 + ccol * 8,
                        Asm + chunk * 512);
            gload_lds16((const unsigned short*)Wt + (size_t)(n0 + row) * Kd + k0 + ccol * 8,
                        Bsm + chunk * 512);
        }
        __syncthreads();

        bf16x8 af[4], bg[4];
#pragma unroll
        for (int i = 0; i < 4; i++)
            af[i] = *(const bf16x8*)(Asm + (wm + i * 16 + qm) * 32 + quad * 8);
#pragma unroll
        for (int j = 0; j < 4; j++)
            bg[j] = *(const bf16x8*)(Bsm + (wn + j * 16 + qm) * 32 + quad * 8);
#pragma unroll
        for (int i = 0; i < 4; i++)
#pragma unroll
            for (int j = 0; j < 4; j++)
                acc[i][j] = __builtin_amdgcn_mfma_f32_16x16x32_bf16(
                    af[i], bg[j], acc[i][j], 0, 0, 0);
        __syncthreads();
    }

    // epilogue: C/D layout col=lane&15, row=quad*4+reg
#pragma unroll
    for (int i = 0; i < 4; i++) {
#pragma unroll
        for (int j = 0; j < 4; j++) {
            int col = n0 + wn + j * 16 + qm;
            int rowb = m0 + wm + i * 16 + quad * 4;
            if (PERM && z == 2) {
                // V -> Vt [bh][d][s]: rows r are consecutive s, pack 4 bf16
                int b = rowb >> 11, s = rowb & (S_ - 1);
                int h = col >> 6, d = col & (D_ - 1);
                unsigned short pk4[4];
#pragma unroll
                for (int r = 0; r < 4; r++) pk4[r] = f2bf_u(acc[i][j][r] + bvv[j]);
                uint2 pv;
                pv.x = (unsigned)pk4[0] | ((unsigned)pk4[1] << 16);
                pv.y = (unsigned)pk4[2] | ((unsigned)pk4[3] << 16);
                *(uint2*)((unsigned short*)outB +
                          ((size_t)(b * H_ + h) * D_ + d) * S_ + s) = pv;
            } else {
#pragma unroll
                for (int r = 0; r < 4; r++) {
                    int row = rowb + r;
                    float val = acc[i][j][r] + bvv[j];
                    if (PERM) {
                        int b = row >> 11, s = row & (S_ - 1);
                        int h = col >> 6, d = col & (D_ - 1);
                        outB[(((size_t)(b * H_ + h)) * S_ + s) * D_ + d] = f2bf(val);
                    } else {
                        outF[(size_t)row * N + col] = val;
                    }
                }
            }
        }
    }
}

// ---------------------------------------------------------------------------
// Flash attention (S^T formulation, analytic-max softmax, causal + ALiBi).
// R14: R11 structure (LDS staging is the block-level K/V de-dup - R13's
// direct-L2 reads quadrupled request rate and regressed 2.3x) plus the
// m201-proven COUNTED-VMCNT double-buffer:
//   - K/V double-buffered; stage(kt+1) issued at top of iteration kt.
//   - raw s_barrier + inline-asm s_waitcnt vmcnt(4): wait only for kt's 4
//     staging loads, kt+1's 4 stay IN FLIGHT across both barriers and the
//     whole compute phase (this is what __syncthreads structurally cannot
//     do - it drains vmcnt to 0, which is why R11 stalled and R12's dbuf
//     was null).
//   - Q fragment loads drained pre-loop so the compiler needs no vmcnt
//     in the loop body.
// Paired q-tiles, swizzled K/V + P, split PsmH/PsmL kept. LDS 48KB,
// 3 blocks/CU (grid-capped). No setprio (single-variable discipline).
// ---------------------------------------------------------------------------
__global__ __launch_bounds__(256, 3) void attn_k(
    const __bf16* __restrict__ Q, const __bf16* __restrict__ K,
    const __bf16* __restrict__ Vt, __bf16* __restrict__ O) {
    __shared__ alignas(16) __bf16 Ksm[2][2][64 * 32];  // [buf][dhalf][key][d%32] swz
    __shared__ alignas(16) __bf16 Vsm[2][2][64 * 32];  // [buf][khalf][d][key%32] swz
    __shared__ alignas(16) __bf16 PsmH[4 * 16 * 64];   // per-wave P (H tile)
    __shared__ alignas(16) __bf16 PsmL[4 * 16 * 64];   // per-wave P (L tile)

    const int t = threadIdx.x;
    const int w = t >> 6, lane = t & 63;
    const int qm = lane & 15, quad = lane >> 4;
    const int xp = blockIdx.y;                    // pair id 0..15
    const int qlo = xp, qhi = 31 - xp;            // (xp+1) + (32-xp) = 33 tiles
    const int bh = blockIdx.x;
    const float c2 = c_slopes[bh % H_] * 1.44269504f;     // slope * log2(e)
    const size_t base = (size_t)bh * S_ * D_;

    // Q B-fragments for both tiles (lane qm = q-col, contiguous over d)
    const int bbL = qlo * 64 + w * 16;
    const int bbH = qhi * 64 + w * 16;
    const __bf16* qpL = Q + base + (size_t)(bbL + qm) * D_ + quad * 8;
    const __bf16* qpH = Q + base + (size_t)(bbH + qm) * D_ + quad * 8;
    bf16x8 qL0 = *(const bf16x8*)qpL, qL1 = *(const bf16x8*)(qpL + 32);
    bf16x8 qH0 = *(const bf16x8*)qpH, qH1 = *(const bf16x8*)(qpH + 32);
    // drain Q loads now: loop body then contains no compiler-inserted vmcnt
    asm volatile("s_waitcnt vmcnt(0)" ::: "memory");

    f32x4 oaccL[4] = {}, oaccH[4] = {};
    float lsumL = 0.f, lsumH = 0.f;
    char* PbH = (char*)PsmH + w * 2048;           // wave's 16x128B region
    char* PbL = (char*)PsmL + w * 2048;

    // gload staging: wave w stages rows 16w..16w+15 of each array.
    // Source quarter pre-swizzled so LDS slot (r,c) holds global quarter
    // c ^ ((r&15)>>1 & 3)  (dest is HW-linear: base + lane*16).
    const int srow = lane >> 2;
    const int sq = (lane & 3) ^ ((lane >> 3) & 3);
    const unsigned short* Kg = (const unsigned short*)K + base +
                               (size_t)(16 * w + srow) * D_ + sq * 8;
    const unsigned short* Vg = (const unsigned short*)Vt + base +
                               (size_t)(16 * w + srow) * S_ + sq * 8;

    // swizzled read quarter (elems): global quarter `quad` of row (16i+qm)
    const int cq = (quad ^ ((qm >> 1) & 3)) * 8;
    // P swizzle: byte bits[6:4] ^= qm&7 within each 128B row
    const int pf = (qm & 7) << 4;

    int kt = 0;  // captured by tile lambda

    auto stage = [&](int buf, int k) {    // exactly 4 VMEM ops per wave
#pragma unroll
        for (int h = 0; h < 2; h++) {
            gload_lds16(Kg + (size_t)(k * 64) * D_ + 32 * h,
                        Ksm[buf][h] + w * 512);
            gload_lds16(Vg + k * 64 + 32 * h, Vsm[buf][h] + w * 512);
        }
    };

    bf16x8 ak[4][2], bv[4][2];
    auto tilec = [&](const bf16x8& qf0, const bf16x8& qf1, f32x4* oacc,
                     float& lsum, int bb, char* Pb) {
        // S^T = K Q^T : lane (qm,quad) reg r holds S^T[key=16i+4quad+r][q=qm]
        f32x4 st[4];
#pragma unroll
        for (int i = 0; i < 4; i++) {
            f32x4 zz = {0.f, 0.f, 0.f, 0.f};
            zz = __builtin_amdgcn_mfma_f32_16x16x32_bf16(ak[i][0], qf0, zz, 0, 0, 0);
            zz = __builtin_amdgcn_mfma_f32_16x16x32_bf16(ak[i][1], qf1, zz, 0, 0, 0);
            st[i] = zz;
        }

        // analytic-max softmax: exponent = qk*scale*log2e - c2*key
        const int qi = bb + qm;
        const bool nomask = (kt * 64 + 63) <= bb;
        float ls = 0.f;
        unsigned pk[4][2];
#pragma unroll
        for (int i = 0; i < 4; i++) {
            float bi = -c2 * (float)(kt * 64 + 16 * i + 4 * quad);
            float p[4];
#pragma unroll
            for (int r = 0; r < 4; r++) {
                float tt = st[i][r] * 0.18033688f + (bi - c2 * (float)r);
                float pp = __builtin_amdgcn_exp2f(tt);
                if (!nomask) {
                    int key = kt * 64 + 16 * i + 4 * quad + r;
                    pp = (key > qi) ? 0.f : pp;
                }
                ls += pp;
                p[r] = pp;
            }
            // pack 4 fp32 -> 4 bf16 (round-half-up + v_perm byte select)
            unsigned u0 = __builtin_bit_cast(unsigned, p[0]) + 0x8000u;
            unsigned u1 = __builtin_bit_cast(unsigned, p[1]) + 0x8000u;
            unsigned u2 = __builtin_bit_cast(unsigned, p[2]) + 0x8000u;
            unsigned u3 = __builtin_bit_cast(unsigned, p[3]) + 0x8000u;
            pk[i][0] = __builtin_amdgcn_perm(u1, u0, 0x07060302u);
            pk[i][1] = __builtin_amdgcn_perm(u3, u2, 0x07060302u);
        }
        lsum += ls;

        // P[q=qm][key=16i+4quad+{0..3}] : b64 writes, swizzled within row
#pragma unroll
        for (int i = 0; i < 4; i++) {
            uint2 pv; pv.x = pk[i][0]; pv.y = pk[i][1];
            *(uint2*)(Pb + qm * 128 + ((32 * i + 8 * quad) ^ pf)) = pv;
        }

        // O += P V : A = P rows (b128, swizzled), B = V^T rows
        bf16x8 ap0 = *(const bf16x8*)(Pb + qm * 128 + ((quad * 16) ^ pf));
        bf16x8 ap1 = *(const bf16x8*)(Pb + qm * 128 + ((64 + quad * 16) ^ pf));
#pragma unroll
        for (int jd = 0; jd < 4; jd++) {
            oacc[jd] = __builtin_amdgcn_mfma_f32_16x16x32_bf16(
                ap0, bv[jd][0], oacc[jd], 0, 0, 0);
            oacc[jd] = __builtin_amdgcn_mfma_f32_16x16x32_bf16(
                ap1, bv[jd][1], oacc[jd], 0, 0, 0);
        }
    };

    stage(0, 0);
    for (kt = 0; kt <= qhi; kt++) {
        const int cur = kt & 1;
        if (kt < qhi) {
            stage(cur ^ 1, kt + 1);                       // 4 new VMEM in flight
            asm volatile("s_waitcnt vmcnt(4)" ::: "memory");  // kt's 4 landed
        } else {
            asm volatile("s_waitcnt vmcnt(0)" ::: "memory");
        }
        __builtin_amdgcn_s_barrier();   // all waves' buf[cur] writes visible

        // K A-frags (m=key) and V B-frags (n=d), swizzled quarter reads
#pragma unroll
        for (int i = 0; i < 4; i++) {
            ak[i][0] = *(const bf16x8*)(Ksm[cur][0] + (16 * i + qm) * 32 + cq);
            ak[i][1] = *(const bf16x8*)(Ksm[cur][1] + (16 * i + qm) * 32 + cq);
        }
#pragma unroll
        for (int jd = 0; jd < 4; jd++) {
            bv[jd][0] = *(const bf16x8*)(Vsm[cur][0] + (16 * jd + qm) * 32 + cq);
            bv[jd][1] = *(const bf16x8*)(Vsm[cur][1] + (16 * jd + qm) * 32 + cq);
        }

        tilec(qH0, qH1, oaccH, lsumH, bbH, PbH);             // always
        if (kt <= qlo) tilec(qL0, qL1, oaccL, lsumL, bbL, PbL);  // uniform branch

        __builtin_amdgcn_s_barrier();   // reads of buf[cur] done before kt+1
                                        // restages it (writes land post-issue)
    }

    // epilogue: reduce l across quads (lane-local rows), divide, store
    auto epi = [&](f32x4* oacc, float lsum, int bb) {
        float lf = lsum;
        lf += __shfl_xor(lf, 16);
        lf += __shfl_xor(lf, 32);               // full l for q = bb+qm
#pragma unroll
        for (int r = 0; r < 4; r++) {
            float lr = __shfl(lf, 4 * quad + r);  // l for q = bb+4quad+r
            float inv = 1.0f / lr;
            int qrow = bb + 4 * quad + r;
#pragma unroll
            for (int jd = 0; jd < 4; jd++)
                O[base + (size_t)qrow * D_ + 16 * jd + qm] =
                    f2bf(oacc[jd][r] * inv);
        }
    };
    epi(oaccH, lsumH, bbH);
    epi(oaccL, lsumL, bbL);
}

// ---------------------------------------------------------------------------
extern "C" void kernel_launch(void* const* d_in, const int* in_sizes, int n_in,
                              void* d_out, int out_size, void* d_ws, size_t ws_size,
                              hipStream_t stream) {
    (void)in_sizes; (void)n_in; (void)out_size; (void)ws_size;
    const float* x  = (const float*)d_in[0];
    const float* Wq = (const float*)d_in[1];
    const float* bq = (const float*)d_in[2];
    const float* Wk = (const float*)d_in[3];
    const float* bk = (const float*)d_in[4];
    const float* Wv = (const float*)d_in[5];
    const float* bv = (const float*)d_in[6];
    const float* Wo = (const float*)d_in[7];
    const float* bo = (const float*)d_in[8];
    float* out = (float*)d_out;

    const size_t n = (size_t)B_ * H_ * S_ * D_;  // 6291456
    // ws layout (46 MB):
    //  [0,n):   xb (dead after QKV gemm)
    //  [n,2n):  Qb -> Ob (attn reads only its own Q rows before writing them)
    //  [2n,3n): Kb
    //  [3n,4n): Vtb  (V written transposed by QKV gemm epilogue, z=2)
    //  [4n,+):  Wt, 4 x 768*768 bf16
    __bf16* xb  = (__bf16*)d_ws;
    __bf16* Qb  = xb + n;
    __bf16* Kb  = xb + 2 * n;
    __bf16* Vtb = xb + 3 * n;
    __bf16* Wt  = xb + 4 * n;
    __bf16* Ob  = Qb;

    cvt_x<<<6144, 256, 0, stream>>>(x, xb);
    wtrans<<<dim3(12, 12, 4), 256, 0, stream>>>(Wq, Wk, Wv, Wo, Wt);
    gemm_bf<true><<<dim3(6, 64, 3), 256, 0, stream>>>(
        xb, Wt, bq, bk, bv, nullptr, Qb);
    attn_k<<<dim3(48, 16), 256, 0, stream>>>(Qb, Kb, Vtb, Ob);
    gemm_bf<false><<<dim3(6, 64, 1), 256, 0, stream>>>(
        Ob, Wt + 3 * (size_t)E_ * E_, bo, nullptr, nullptr, out, nullptr);
}

// Round 6
// 237.720 us; speedup vs baseline: 1.4812x; 1.1010x over previous
//
#include <hip/hip_runtime.h>
#include <hip/hip_bf16.h>
#include <cstdint>
#include <cstddef>

#define B_ 4
#define S_ 2048
#define E_ 768
#define H_ 12
#define D_ 64

typedef __bf16 bf16x8 __attribute__((ext_vector_type(8)));
typedef float f32x4 __attribute__((ext_vector_type(4)));

__constant__ float c_slopes[12] = {
    0.6299605249f, 0.396850263f, 0.25f, 0.1574901312f,
    0.0992125657f, 0.0625f, 0.0393725328f, 0.0248031414f,
    0.015625f, 0.0098431332f, 0.0062007854f, 0.00390625f};

__device__ __forceinline__ unsigned short f2bf_u(float f) {
    unsigned u = __builtin_bit_cast(unsigned, f);
    u += 0x7fffu + ((u >> 16) & 1u);   // round-to-nearest-even
    return (unsigned short)(u >> 16);
}
__device__ __forceinline__ __bf16 f2bf(float f) {
    unsigned short s = f2bf_u(f);
    return __builtin_bit_cast(__bf16, s);
}

// async global->LDS, 16B per lane, dest = wave-uniform base + lane*16
__device__ __forceinline__ void gload_lds16(const void* g, void* l) {
    __builtin_amdgcn_global_load_lds(
        (const __attribute__((address_space(1))) unsigned int*)g,
        (__attribute__((address_space(3))) unsigned int*)l, 16, 0, 0);
}

// ---------------------------------------------------------------------------
// prep: x fp32 -> bf16 (6.29M elems)
// ---------------------------------------------------------------------------
__global__ __launch_bounds__(256) void cvt_x(const float* __restrict__ src,
                                             __bf16* __restrict__ dst) {
    int i = (blockIdx.x * 256 + threadIdx.x) * 4;
    float4 v = *(const float4*)(src + i);
    ushort4 o;
    o.x = f2bf_u(v.x); o.y = f2bf_u(v.y); o.z = f2bf_u(v.z); o.w = f2bf_u(v.w);
    *(ushort4*)((unsigned short*)dst + i) = o;
}

// ---------------------------------------------------------------------------
// prep: W fp32 [k][n] -> Wt bf16 [n][k]; z picks which of 4 matrices
// ---------------------------------------------------------------------------
__global__ __launch_bounds__(256) void wtrans(const float* __restrict__ W0,
                                              const float* __restrict__ W1,
                                              const float* __restrict__ W2,
                                              const float* __restrict__ W3,
                                              __bf16* __restrict__ Wt) {
    const float* W = blockIdx.z == 0 ? W0 : blockIdx.z == 1 ? W1
                   : blockIdx.z == 2 ? W2 : W3;
    __bf16* out = Wt + (size_t)blockIdx.z * E_ * E_;
    __shared__ alignas(16) __bf16 ts[64 * 72];
    const int t = threadIdx.x;
    const int k0 = blockIdx.y * 64, n0 = blockIdx.x * 64;
#pragma unroll
    for (int i = 0; i < 4; i++) {
        int idx = i * 256 + t;          // 1024 float4 chunks
        int row = idx >> 4, c4 = idx & 15;
        float4 v = *(const float4*)(W + (size_t)(k0 + row) * E_ + n0 + c4 * 4);
        ts[(c4 * 4 + 0) * 72 + row] = f2bf(v.x);
        ts[(c4 * 4 + 1) * 72 + row] = f2bf(v.y);
        ts[(c4 * 4 + 2) * 72 + row] = f2bf(v.z);
        ts[(c4 * 4 + 3) * 72 + row] = f2bf(v.w);
    }
    __syncthreads();
#pragma unroll
    for (int i = 0; i < 2; i++) {
        int idx = i * 256 + t;          // 512 chunks of 8 bf16
        int r = idx >> 3, c8 = idx & 7;
        *(uint4*)((unsigned short*)out + (size_t)(n0 + r) * E_ + k0 + c8 * 8) =
            *(const uint4*)((const unsigned short*)ts + r * 72 + c8 * 8);
    }
}

// ---------------------------------------------------------------------------
// GEMM: out = A(8192x768 bf16) @ Wt^T + bias. Wt is [n][k] bf16.
// R7 single-BK32 m97-style staging (best measured). Bias prefetched into
// registers before the K-loop (scattered 4B loads were latency-exposed in
// the epilogue). z=2 -> V written transposed [bh][d][s].
// ---------------------------------------------------------------------------
template <bool PERM>
__global__ __launch_bounds__(256) void gemm_bf(
    const __bf16* __restrict__ A, const __bf16* __restrict__ WtAll,
    const float* __restrict__ b0, const float* __restrict__ b1,
    const float* __restrict__ b2,
    float* __restrict__ outF, __bf16* __restrict__ outB_base) {
    constexpr int Kd = E_, N = E_;
    __shared__ alignas(16) __bf16 Asm[128 * 32];   // 64B rows, no pad (m97)
    __shared__ alignas(16) __bf16 Bsm[128 * 32];

    const int t = threadIdx.x;
    const int w = t >> 6, lane = t & 63;
    const int qm = lane & 15, quad = lane >> 4;
    const int m0 = blockIdx.y * 128, n0 = blockIdx.x * 128;
    const int wm = (w >> 1) * 64, wn = (w & 1) * 64;
    const int z = blockIdx.z;
    const __bf16* Wt = WtAll + (size_t)z * Kd * N;
    const float* bias = PERM ? (z == 0 ? b0 : z == 1 ? b1 : b2) : b0;
    __bf16* outB = PERM ? outB_base + (size_t)z * ((size_t)B_ * S_ * E_) : nullptr;

    // bias prefetch: 4 scattered loads issued before the K-loop
    float bvv[4];
#pragma unroll
    for (int j = 0; j < 4; j++) bvv[j] = bias[n0 + wn + j * 16 + qm];

    // staging: 1024B wave-chunk = 16 rows x 64B; wave w owns chunks {2w,2w+1}
    const int crow = lane >> 2;       // row within chunk
    const int ccol = lane & 3;        // 16B quarter within row

    f32x4 acc[4][4] = {};

    for (int k0 = 0; k0 < Kd; k0 += 32) {
#pragma unroll
        for (int cc = 0; cc < 2; cc++) {
            int chunk = w * 2 + cc;
            int row = chunk * 16 + crow;
            gload_lds16((const unsigned short*)A + (size_t)(m0 + row) * Kd + k0 + ccol * 8,
                        Asm + chunk * 512);
            gload_lds16((const unsigned short*)Wt + (size_t)(n0 + row) * Kd + k0 + ccol * 8,
                        Bsm + chunk * 512);
        }
        __syncthreads();

        bf16x8 af[4], bg[4];
#pragma unroll
        for (int i = 0; i < 4; i++)
            af[i] = *(const bf16x8*)(Asm + (wm + i * 16 + qm) * 32 + quad * 8);
#pragma unroll
        for (int j = 0; j < 4; j++)
            bg[j] = *(const bf16x8*)(Bsm + (wn + j * 16 + qm) * 32 + quad * 8);
#pragma unroll
        for (int i = 0; i < 4; i++)
#pragma unroll
            for (int j = 0; j < 4; j++)
                acc[i][j] = __builtin_amdgcn_mfma_f32_16x16x32_bf16(
                    af[i], bg[j], acc[i][j], 0, 0, 0);
        __syncthreads();
    }

    // epilogue: C/D layout col=lane&15, row=quad*4+reg
#pragma unroll
    for (int i = 0; i < 4; i++) {
#pragma unroll
        for (int j = 0; j < 4; j++) {
            int col = n0 + wn + j * 16 + qm;
            int rowb = m0 + wm + i * 16 + quad * 4;
            if (PERM && z == 2) {
                // V -> Vt [bh][d][s]: rows r are consecutive s, pack 4 bf16
                int b = rowb >> 11, s = rowb & (S_ - 1);
                int h = col >> 6, d = col & (D_ - 1);
                unsigned short pk4[4];
#pragma unroll
                for (int r = 0; r < 4; r++) pk4[r] = f2bf_u(acc[i][j][r] + bvv[j]);
                uint2 pv;
                pv.x = (unsigned)pk4[0] | ((unsigned)pk4[1] << 16);
                pv.y = (unsigned)pk4[2] | ((unsigned)pk4[3] << 16);
                *(uint2*)((unsigned short*)outB +
                          ((size_t)(b * H_ + h) * D_ + d) * S_ + s) = pv;
            } else {
#pragma unroll
                for (int r = 0; r < 4; r++) {
                    int row = rowb + r;
                    float val = acc[i][j][r] + bvv[j];
                    if (PERM) {
                        int b = row >> 11, s = row & (S_ - 1);
                        int h = col >> 6, d = col & (D_ - 1);
                        outB[(((size_t)(b * H_ + h)) * S_ + s) * D_ + d] = f2bf(val);
                    } else {
                        outF[(size_t)row * N + col] = val;
                    }
                }
            }
        }
    }
}

// ---------------------------------------------------------------------------
// Flash attention (S^T formulation, analytic-max softmax, causal + ALiBi).
// R15: UNPAIRED + BALANCED SWIZZLE + 6 blocks/CU. R0 (unpaired, 6/CU) was
// 101us DESPITE 1.9x per-CU qt-imbalance; R11's pairing balanced it (81us)
// but halved waves/SIMD to 3 - and all pipelining attempts at 3 waves/SIMD
// nulled (R12/R14): TLP is the binding constraint. This kernel restores
// 6144 waves (16 q-rows each) = 6 waves/SIMD co-resident, and fixes R0's
// imbalance IN THE MAPPING: with dispatch CU = L mod 256 (observed in R0)
// and XCD = L mod 8 (guide m09/m157):
//   r=L&7 -> XCD; bh = r*6 + (L>>8): 6 fixed heads per XCD (3MB K/V < 4MB
//   L2, same locality as R11); qt = (m + s*5 + (s>>1)) & 31 gives the 6
//   co-resident slots qt-offsets {0,5,11,16,22,27}: per-CU work in
//   [77,107] vs avg 93 (1.15x stretch vs R0's 1.9x).
// Body = R11's proven single-buffer 2-barrier loop (beat both dbuf
// variants) with K/V+P swizzles. LDS 24KB x 6 = 144KB/CU; VGPR ~40-50
// (unpaired) well under the 85 needed for 6 waves/SIMD.
// ---------------------------------------------------------------------------
__global__ __launch_bounds__(256, 6) void attn_k(
    const __bf16* __restrict__ Q, const __bf16* __restrict__ K,
    const __bf16* __restrict__ Vt, __bf16* __restrict__ O) {
    __shared__ alignas(16) __bf16 Ksm[2][64 * 32];   // [dhalf][key][d%32] swz
    __shared__ alignas(16) __bf16 Vsm[2][64 * 32];   // [khalf][d][key%32] swz
    __shared__ alignas(16) __bf16 Psm[4 * 16 * 64];  // per-wave P, 128B rows swz

    const int t = threadIdx.x;
    const int w = t >> 6, lane = t & 63;
    const int qm = lane & 15, quad = lane >> 4;
    // balanced XCD-local block swizzle
    const int L = blockIdx.x;
    const int r = L & 7;            // XCD (round-robin assumption, m09/m157)
    const int m = (L >> 3) & 31;    // CU within XCD
    const int s = L >> 8;           // co-resident slot 0..5
    const int bh = r * 6 + s;       // 6 fixed heads per XCD
    const int qt = (m + s * 5 + (s >> 1)) & 31;  // slot offsets {0,5,11,16,22,27}
    const float c2 = c_slopes[bh % H_] * 1.44269504f;     // slope * log2(e)
    const size_t base = (size_t)bh * S_ * D_;

    // Q B-fragments (lane qm = q-col, contiguous over d)
    const int bb = qt * 64 + w * 16;
    const __bf16* qp = Q + base + (size_t)(bb + qm) * D_ + quad * 8;
    bf16x8 qf0 = *(const bf16x8*)qp;
    bf16x8 qf1 = *(const bf16x8*)(qp + 32);

    f32x4 oacc[4] = {};
    float lsum = 0.f;
    char* Pb = (char*)Psm + w * 2048;             // wave's 16x128B region

    // gload staging: wave w stages rows 16w..16w+15 of each array.
    // Source quarter pre-swizzled so LDS slot (r,c) holds global quarter
    // c ^ ((r&15)>>1 & 3)  (dest is HW-linear: base + lane*16).
    const int srow = lane >> 2;
    const int sq = (lane & 3) ^ ((lane >> 3) & 3);
    const unsigned short* Kg = (const unsigned short*)K + base +
                               (size_t)(16 * w + srow) * D_ + sq * 8;
    const unsigned short* Vg = (const unsigned short*)Vt + base +
                               (size_t)(16 * w + srow) * S_ + sq * 8;

    // swizzled read quarter (elems): global quarter `quad` of row (16i+qm)
    const int cq = (quad ^ ((qm >> 1) & 3)) * 8;
    // P swizzle: byte bits[6:4] ^= qm&7 within each 128B row
    const int pf = (qm & 7) << 4;

    for (int kt = 0; kt <= qt; kt++) {
        // async stage into LDS (block-level K/V de-dup: 1 copy serves 4 waves)
#pragma unroll
        for (int h = 0; h < 2; h++) {
            gload_lds16(Kg + (size_t)(kt * 64) * D_ + 32 * h, Ksm[h] + w * 512);
            gload_lds16(Vg + kt * 64 + 32 * h, Vsm[h] + w * 512);
        }
        __syncthreads();   // (compiler inserts vmcnt(0) drain before barrier)

        // K A-frags (m=key) and V B-frags (n=d), swizzled quarter reads
        bf16x8 ak[4][2], bv[4][2];
#pragma unroll
        for (int i = 0; i < 4; i++) {
            ak[i][0] = *(const bf16x8*)(Ksm[0] + (16 * i + qm) * 32 + cq);
            ak[i][1] = *(const bf16x8*)(Ksm[1] + (16 * i + qm) * 32 + cq);
        }
#pragma unroll
        for (int jd = 0; jd < 4; jd++) {
            bv[jd][0] = *(const bf16x8*)(Vsm[0] + (16 * jd + qm) * 32 + cq);
            bv[jd][1] = *(const bf16x8*)(Vsm[1] + (16 * jd + qm) * 32 + cq);
        }

        // S^T = K Q^T : lane (qm,quad) reg r holds S^T[key=16i+4quad+r][q=qm]
        f32x4 st[4];
#pragma unroll
        for (int i = 0; i < 4; i++) {
            f32x4 zz = {0.f, 0.f, 0.f, 0.f};
            zz = __builtin_amdgcn_mfma_f32_16x16x32_bf16(ak[i][0], qf0, zz, 0, 0, 0);
            zz = __builtin_amdgcn_mfma_f32_16x16x32_bf16(ak[i][1], qf1, zz, 0, 0, 0);
            st[i] = zz;
        }

        // analytic-max softmax: exponent = qk*scale*log2e - c2*key
        const int qi = bb + qm;
        const bool nomask = (kt * 64 + 63) <= bb;
        float ls = 0.f;
        unsigned pk[4][2];
#pragma unroll
        for (int i = 0; i < 4; i++) {
            float bi = -c2 * (float)(kt * 64 + 16 * i + 4 * quad);
            float p[4];
#pragma unroll
            for (int rr = 0; rr < 4; rr++) {
                float tt = st[i][rr] * 0.18033688f + (bi - c2 * (float)rr);
                float pp = __builtin_amdgcn_exp2f(tt);
                if (!nomask) {
                    int key = kt * 64 + 16 * i + 4 * quad + rr;
                    pp = (key > qi) ? 0.f : pp;
                }
                ls += pp;
                p[rr] = pp;
            }
            // pack 4 fp32 -> 4 bf16 (round-half-up + v_perm byte select)
            unsigned u0 = __builtin_bit_cast(unsigned, p[0]) + 0x8000u;
            unsigned u1 = __builtin_bit_cast(unsigned, p[1]) + 0x8000u;
            unsigned u2 = __builtin_bit_cast(unsigned, p[2]) + 0x8000u;
            unsigned u3 = __builtin_bit_cast(unsigned, p[3]) + 0x8000u;
            pk[i][0] = __builtin_amdgcn_perm(u1, u0, 0x07060302u);
            pk[i][1] = __builtin_amdgcn_perm(u3, u2, 0x07060302u);
        }
        lsum += ls;

        // P[q=qm][key=16i+4quad+{0..3}] : b64 writes, swizzled within row
#pragma unroll
        for (int i = 0; i < 4; i++) {
            uint2 pv; pv.x = pk[i][0]; pv.y = pk[i][1];
            *(uint2*)(Pb + qm * 128 + ((32 * i + 8 * quad) ^ pf)) = pv;
        }

        // O += P V : A = P rows (b128, swizzled), B = V^T rows
        bf16x8 ap0 = *(const bf16x8*)(Pb + qm * 128 + ((quad * 16) ^ pf));
        bf16x8 ap1 = *(const bf16x8*)(Pb + qm * 128 + ((64 + quad * 16) ^ pf));
#pragma unroll
        for (int jd = 0; jd < 4; jd++) {
            oacc[jd] = __builtin_amdgcn_mfma_f32_16x16x32_bf16(
                ap0, bv[jd][0], oacc[jd], 0, 0, 0);
            oacc[jd] = __builtin_amdgcn_mfma_f32_16x16x32_bf16(
                ap1, bv[jd][1], oacc[jd], 0, 0, 0);
        }

        __syncthreads();   // protect buffers before next iteration's gloads
    }

    // epilogue: reduce l across quads (lane-local rows), divide, store
    float lf = lsum;
    lf += __shfl_xor(lf, 16);
    lf += __shfl_xor(lf, 32);               // full l for q = bb+qm
#pragma unroll
    for (int rr = 0; rr < 4; rr++) {
        float lr = __shfl(lf, 4 * quad + rr);  // l for q = bb+4quad+rr
        float inv = 1.0f / lr;
        int qrow = bb + 4 * quad + rr;
#pragma unroll
        for (int jd = 0; jd < 4; jd++)
            O[base + (size_t)qrow * D_ + 16 * jd + qm] =
                f2bf(oacc[jd][rr] * inv);
    }
}

// ---------------------------------------------------------------------------
extern "C" void kernel_launch(void* const* d_in, const int* in_sizes, int n_in,
                              void* d_out, int out_size, void* d_ws, size_t ws_size,
                              hipStream_t stream) {
    (void)in_sizes; (void)n_in; (void)out_size; (void)ws_size;
    const float* x  = (const float*)d_in[0];
    const float* Wq = (const float*)d_in[1];
    const float* bq = (const float*)d_in[2];
    const float* Wk = (const float*)d_in[3];
    const float* bk = (const float*)d_in[4];
    const float* Wv = (const float*)d_in[5];
    const float* bv = (const float*)d_in[6];
    const float* Wo = (const float*)d_in[7];
    const float* bo = (const float*)d_in[8];
    float* out = (float*)d_out;

    const size_t n = (size_t)B_ * H_ * S_ * D_;  // 6291456
    // ws layout (46 MB):
    //  [0,n):   xb (dead after QKV gemm)
    //  [n,2n):  Qb -> Ob (attn reads only its own Q rows before writing them)
    //  [2n,3n): Kb
    //  [3n,4n): Vtb  (V written transposed by QKV gemm epilogue, z=2)
    //  [4n,+):  Wt, 4 x 768*768 bf16
    __bf16* xb  = (__bf16*)d_ws;
    __bf16* Qb  = xb + n;
    __bf16* Kb  = xb + 2 * n;
    __bf16* Vtb = xb + 3 * n;
    __bf16* Wt  = xb + 4 * n;
    __bf16* Ob  = Qb;

    cvt_x<<<6144, 256, 0, stream>>>(x, xb);
    wtrans<<<dim3(12, 12, 4), 256, 0, stream>>>(Wq, Wk, Wv, Wo, Wt);
    gemm_bf<true><<<dim3(6, 64, 3), 256, 0, stream>>>(
        xb, Wt, bq, bk, bv, nullptr, Qb);
    attn_k<<<1536, 256, 0, stream>>>(Qb, Kb, Vtb, Ob);
    gemm_bf<false><<<dim3(6, 64, 1), 256, 0, stream>>>(
        Ob, Wt + 3 * (size_t)E_ * E_, bo, nullptr, nullptr, out, nullptr);
}

// Round 7
// 218.480 us; speedup vs baseline: 1.6116x; 1.0881x over previous
//
#include <hip/hip_runtime.h>
#include <hip/hip_bf16.h>
#include <cstdint>
#include <cstddef>

#define B_ 4
#define S_ 2048
#define E_ 768
#define H_ 12
#define D_ 64

typedef __bf16 bf16x8 __attribute__((ext_vector_type(8)));
typedef float f32x4 __attribute__((ext_vector_type(4)));

__constant__ float c_slopes[12] = {
    0.6299605249f, 0.396850263f, 0.25f, 0.1574901312f,
    0.0992125657f, 0.0625f, 0.0393725328f, 0.0248031414f,
    0.015625f, 0.0098431332f, 0.0062007854f, 0.00390625f};

__device__ __forceinline__ unsigned short f2bf_u(float f) {
    unsigned u = __builtin_bit_cast(unsigned, f);
    u += 0x7fffu + ((u >> 16) & 1u);   // round-to-nearest-even
    return (unsigned short)(u >> 16);
}
__device__ __forceinline__ __bf16 f2bf(float f) {
    unsigned short s = f2bf_u(f);
    return __builtin_bit_cast(__bf16, s);
}

// async global->LDS, 16B per lane, dest = wave-uniform base + lane*16
__device__ __forceinline__ void gload_lds16(const void* g, void* l) {
    __builtin_amdgcn_global_load_lds(
        (const __attribute__((address_space(1))) unsigned int*)g,
        (__attribute__((address_space(3))) unsigned int*)l, 16, 0, 0);
}

// ---------------------------------------------------------------------------
// prep: x fp32 -> bf16 (6.29M elems)
// ---------------------------------------------------------------------------
__global__ __launch_bounds__(256) void cvt_x(const float* __restrict__ src,
                                             __bf16* __restrict__ dst) {
    int i = (blockIdx.x * 256 + threadIdx.x) * 4;
    float4 v = *(const float4*)(src + i);
    ushort4 o;
    o.x = f2bf_u(v.x); o.y = f2bf_u(v.y); o.z = f2bf_u(v.z); o.w = f2bf_u(v.w);
    *(ushort4*)((unsigned short*)dst + i) = o;
}

// ---------------------------------------------------------------------------
// prep: W fp32 [k][n] -> Wt bf16 [n][k]; z picks which of 4 matrices
// ---------------------------------------------------------------------------
__global__ __launch_bounds__(256) void wtrans(const float* __restrict__ W0,
                                              const float* __restrict__ W1,
                                              const float* __restrict__ W2,
                                              const float* __restrict__ W3,
                                              __bf16* __restrict__ Wt) {
    const float* W = blockIdx.z == 0 ? W0 : blockIdx.z == 1 ? W1
                   : blockIdx.z == 2 ? W2 : W3;
    __bf16* out = Wt + (size_t)blockIdx.z * E_ * E_;
    __shared__ alignas(16) __bf16 ts[64 * 72];
    const int t = threadIdx.x;
    const int k0 = blockIdx.y * 64, n0 = blockIdx.x * 64;
#pragma unroll
    for (int i = 0; i < 4; i++) {
        int idx = i * 256 + t;          // 1024 float4 chunks
        int row = idx >> 4, c4 = idx & 15;
        float4 v = *(const float4*)(W + (size_t)(k0 + row) * E_ + n0 + c4 * 4);
        ts[(c4 * 4 + 0) * 72 + row] = f2bf(v.x);
        ts[(c4 * 4 + 1) * 72 + row] = f2bf(v.y);
        ts[(c4 * 4 + 2) * 72 + row] = f2bf(v.z);
        ts[(c4 * 4 + 3) * 72 + row] = f2bf(v.w);
    }
    __syncthreads();
#pragma unroll
    for (int i = 0; i < 2; i++) {
        int idx = i * 256 + t;          // 512 chunks of 8 bf16
        int r = idx >> 3, c8 = idx & 7;
        *(uint4*)((unsigned short*)out + (size_t)(n0 + r) * E_ + k0 + c8 * 8) =
            *(const uint4*)((const unsigned short*)ts + r * 72 + c8 * 8);
    }
}

// ---------------------------------------------------------------------------
// R16: FUSED QKV GEMM. Block = 128(M) x 64(N) x 3(z): the same x-tile (A)
// is staged ONCE and multiplied against Wq/Wk/Wv tiles in one K-loop.
// vs the old z-split (1152 blocks, 16 MFMA per barrier-pair, A staged 3x):
//   - 24 MFMA/wave per barrier-pair (1.5x amortization of the drain stall)
//   - A-staging traffic / 3
//   - grid 12x64 = 768 blocks = exactly 3/CU: one clean residency round
// acc 3x2x4 f32x4 = 96 VGPR; launch_bounds(256,3) keeps 3 blocks/CU.
// Epilogue per z identical to the proven PERM paths (z=2 -> Vt [bh][d][s]).
// ---------------------------------------------------------------------------
__global__ __launch_bounds__(256, 3) void qkv_gemm(
    const __bf16* __restrict__ A, const __bf16* __restrict__ WtAll,
    const float* __restrict__ b0, const float* __restrict__ b1,
    const float* __restrict__ b2, __bf16* __restrict__ Qb,
    __bf16* __restrict__ Kb, __bf16* __restrict__ Vtb) {
    constexpr int Kd = E_;
    __shared__ alignas(16) __bf16 Asm[128 * 32];     // 8KB
    __shared__ alignas(16) __bf16 Bsm[3][64 * 32];   // 12KB

    const int t = threadIdx.x;
    const int w = t >> 6, lane = t & 63;
    const int qm = lane & 15, quad = lane >> 4;
    const int m0 = blockIdx.y * 128, n0 = blockIdx.x * 64;
    const int wm = w * 32;                 // wave owns 32 rows x 64 cols (x3 z)

    // bias prefetch (12 scattered loads, pre-K-loop)
    float bvv[3][4];
    const float* bs[3] = {b0, b1, b2};
#pragma unroll
    for (int z = 0; z < 3; z++)
#pragma unroll
        for (int j = 0; j < 4; j++) bvv[z][j] = bs[z][n0 + j * 16 + qm];

    const int crow = lane >> 2;       // row within 16-row chunk
    const int ccol = lane & 3;        // 16B quarter within 64B row

    f32x4 acc[3][2][4] = {};

    for (int k0 = 0; k0 < Kd; k0 += 32) {
        // A: 8 chunks of 16 rows; wave w stages {2w, 2w+1}
#pragma unroll
        for (int cc = 0; cc < 2; cc++) {
            int chunk = w * 2 + cc;
            gload_lds16((const unsigned short*)A +
                            (size_t)(m0 + chunk * 16 + crow) * Kd + k0 + ccol * 8,
                        Asm + chunk * 512);
        }
        // B: 3 z x 4 chunks = 12; wave w stages {3w, 3w+1, 3w+2}
#pragma unroll
        for (int e = 0; e < 3; e++) {
            int g = w * 3 + e;
            int z = g >> 2, cz = g & 3;
            gload_lds16((const unsigned short*)WtAll + (size_t)z * Kd * E_ +
                            (size_t)(n0 + cz * 16 + crow) * Kd + k0 + ccol * 8,
                        Bsm[z] + cz * 512);
        }
        __syncthreads();

        bf16x8 af[2];
#pragma unroll
        for (int i = 0; i < 2; i++)
            af[i] = *(const bf16x8*)(Asm + (wm + i * 16 + qm) * 32 + quad * 8);
#pragma unroll
        for (int z = 0; z < 3; z++) {
            bf16x8 bg[4];
#pragma unroll
            for (int j = 0; j < 4; j++)
                bg[j] = *(const bf16x8*)(Bsm[z] + (j * 16 + qm) * 32 + quad * 8);
#pragma unroll
            for (int i = 0; i < 2; i++)
#pragma unroll
                for (int j = 0; j < 4; j++)
                    acc[z][i][j] = __builtin_amdgcn_mfma_f32_16x16x32_bf16(
                        af[i], bg[j], acc[z][i][j], 0, 0, 0);
        }
        __syncthreads();
    }

    // epilogue: C/D layout col=lane&15, row=quad*4+reg
#pragma unroll
    for (int z = 0; z < 3; z++) {
        __bf16* out = z == 0 ? Qb : z == 1 ? Kb : Vtb;
#pragma unroll
        for (int i = 0; i < 2; i++) {
#pragma unroll
            for (int j = 0; j < 4; j++) {
                int col = n0 + j * 16 + qm;
                int rowb = m0 + wm + i * 16 + quad * 4;
                int h = col >> 6, d = col & (D_ - 1);
                if (z == 2) {
                    // V -> Vt [bh][d][s]: rows r consecutive s, pack 4 bf16
                    int b = rowb >> 11, s = rowb & (S_ - 1);
                    unsigned short pk4[4];
#pragma unroll
                    for (int r = 0; r < 4; r++)
                        pk4[r] = f2bf_u(acc[z][i][j][r] + bvv[z][j]);
                    uint2 pv;
                    pv.x = (unsigned)pk4[0] | ((unsigned)pk4[1] << 16);
                    pv.y = (unsigned)pk4[2] | ((unsigned)pk4[3] << 16);
                    *(uint2*)((unsigned short*)out +
                              ((size_t)(b * H_ + h) * D_ + d) * S_ + s) = pv;
                } else {
#pragma unroll
                    for (int r = 0; r < 4; r++) {
                        int row = rowb + r;
                        int b = row >> 11, s = row & (S_ - 1);
                        out[(((size_t)(b * H_ + h)) * S_ + s) * D_ + d] =
                            f2bf(acc[z][i][j][r] + bvv[z][j]);
                    }
                }
            }
        }
    }
}

// ---------------------------------------------------------------------------
// GEMM: out = A(8192x768 bf16) @ Wt^T + bias (fp32 out). Used for the
// output projection only (QKV now fused in qkv_gemm).
// ---------------------------------------------------------------------------
template <bool PERM>
__global__ __launch_bounds__(256) void gemm_bf(
    const __bf16* __restrict__ A, const __bf16* __restrict__ WtAll,
    const float* __restrict__ b0, const float* __restrict__ b1,
    const float* __restrict__ b2,
    float* __restrict__ outF, __bf16* __restrict__ outB_base) {
    constexpr int Kd = E_, N = E_;
    __shared__ alignas(16) __bf16 Asm[128 * 32];   // 64B rows, no pad (m97)
    __shared__ alignas(16) __bf16 Bsm[128 * 32];

    const int t = threadIdx.x;
    const int w = t >> 6, lane = t & 63;
    const int qm = lane & 15, quad = lane >> 4;
    const int m0 = blockIdx.y * 128, n0 = blockIdx.x * 128;
    const int wm = (w >> 1) * 64, wn = (w & 1) * 64;
    const int z = blockIdx.z;
    const __bf16* Wt = WtAll + (size_t)z * Kd * N;
    const float* bias = PERM ? (z == 0 ? b0 : z == 1 ? b1 : b2) : b0;
    __bf16* outB = PERM ? outB_base + (size_t)z * ((size_t)B_ * S_ * E_) : nullptr;

    // bias prefetch: 4 scattered loads issued before the K-loop
    float bvv[4];
#pragma unroll
    for (int j = 0; j < 4; j++) bvv[j] = bias[n0 + wn + j * 16 + qm];

    // staging: 1024B wave-chunk = 16 rows x 64B; wave w owns chunks {2w,2w+1}
    const int crow = lane >> 2;       // row within chunk
    const int ccol = lane & 3;        // 16B quarter within row

    f32x4 acc[4][4] = {};

    for (int k0 = 0; k0 < Kd; k0 += 32) {
#pragma unroll
        for (int cc = 0; cc < 2; cc++) {
            int chunk = w * 2 + cc;
            int row = chunk * 16 + crow;
            gload_lds16((const unsigned short*)A + (size_t)(m0 + row) * Kd + k0 + ccol * 8,
                        Asm + chunk * 512);
            gload_lds16((const unsigned short*)Wt + (size_t)(n0 + row) * Kd + k0 + ccol * 8,
                        Bsm + chunk * 512);
        }
        __syncthreads();

        bf16x8 af[4], bg[4];
#pragma unroll
        for (int i = 0; i < 4; i++)
            af[i] = *(const bf16x8*)(Asm + (wm + i * 16 + qm) * 32 + quad * 8);
#pragma unroll
        for (int j = 0; j < 4; j++)
            bg[j] = *(const bf16x8*)(Bsm + (wn + j * 16 + qm) * 32 + quad * 8);
#pragma unroll
        for (int i = 0; i < 4; i++)
#pragma unroll
            for (int j = 0; j < 4; j++)
                acc[i][j] = __builtin_amdgcn_mfma_f32_16x16x32_bf16(
                    af[i], bg[j], acc[i][j], 0, 0, 0);
        __syncthreads();
    }

    // epilogue: C/D layout col=lane&15, row=quad*4+reg
#pragma unroll
    for (int i = 0; i < 4; i++) {
#pragma unroll
        for (int j = 0; j < 4; j++) {
            int col = n0 + wn + j * 16 + qm;
            int rowb = m0 + wm + i * 16 + quad * 4;
#pragma unroll
            for (int r = 0; r < 4; r++) {
                int row = rowb + r;
                float val = acc[i][j][r] + bvv[j];
                outF[(size_t)row * N + col] = val;
            }
        }
    }
}

// ---------------------------------------------------------------------------
// Flash attention (S^T formulation, analytic-max softmax, causal + ALiBi).
// R15 (kept): UNPAIRED + BALANCED SWIZZLE + 6 blocks/CU. 6144 waves
// (16 q-rows each) = 6 waves/SIMD; balanced per-CU qt via slot offsets
// {0,5,11,16,22,27}; 6 heads per XCD (3MB K/V < 4MB L2). Single-buffer
// 2-barrier loop with K/V+P swizzles. 71us, VALU 47%.
// ---------------------------------------------------------------------------
__global__ __launch_bounds__(256, 6) void attn_k(
    const __bf16* __restrict__ Q, const __bf16* __restrict__ K,
    const __bf16* __restrict__ Vt, __bf16* __restrict__ O) {
    __shared__ alignas(16) __bf16 Ksm[2][64 * 32];   // [dhalf][key][d%32] swz
    __shared__ alignas(16) __bf16 Vsm[2][64 * 32];   // [khalf][d][key%32] swz
    __shared__ alignas(16) __bf16 Psm[4 * 16 * 64];  // per-wave P, 128B rows swz

    const int t = threadIdx.x;
    const int w = t >> 6, lane = t & 63;
    const int qm = lane & 15, quad = lane >> 4;
    // balanced XCD-local block swizzle
    const int L = blockIdx.x;
    const int r = L & 7;            // XCD (round-robin assumption, m09/m157)
    const int m = (L >> 3) & 31;    // CU within XCD
    const int s = L >> 8;           // co-resident slot 0..5
    const int bh = r * 6 + s;       // 6 fixed heads per XCD
    const int qt = (m + s * 5 + (s >> 1)) & 31;  // slot offsets {0,5,11,16,22,27}
    const float c2 = c_slopes[bh % H_] * 1.44269504f;     // slope * log2(e)
    const size_t base = (size_t)bh * S_ * D_;

    // Q B-fragments (lane qm = q-col, contiguous over d)
    const int bb = qt * 64 + w * 16;
    const __bf16* qp = Q + base + (size_t)(bb + qm) * D_ + quad * 8;
    bf16x8 qf0 = *(const bf16x8*)qp;
    bf16x8 qf1 = *(const bf16x8*)(qp + 32);

    f32x4 oacc[4] = {};
    float lsum = 0.f;
    char* Pb = (char*)Psm + w * 2048;             // wave's 16x128B region

    // gload staging: wave w stages rows 16w..16w+15 of each array.
    // Source quarter pre-swizzled so LDS slot (r,c) holds global quarter
    // c ^ ((r&15)>>1 & 3)  (dest is HW-linear: base + lane*16).
    const int srow = lane >> 2;
    const int sq = (lane & 3) ^ ((lane >> 3) & 3);
    const unsigned short* Kg = (const unsigned short*)K + base +
                               (size_t)(16 * w + srow) * D_ + sq * 8;
    const unsigned short* Vg = (const unsigned short*)Vt + base +
                               (size_t)(16 * w + srow) * S_ + sq * 8;

    // swizzled read quarter (elems): global quarter `quad` of row (16i+qm)
    const int cq = (quad ^ ((qm >> 1) & 3)) * 8;
    // P swizzle: byte bits[6:4] ^= qm&7 within each 128B row
    const int pf = (qm & 7) << 4;

    for (int kt = 0; kt <= qt; kt++) {
        // async stage into LDS (block-level K/V de-dup: 1 copy serves 4 waves)
#pragma unroll
        for (int h = 0; h < 2; h++) {
            gload_lds16(Kg + (size_t)(kt * 64) * D_ + 32 * h, Ksm[h] + w * 512);
            gload_lds16(Vg + kt * 64 + 32 * h, Vsm[h] + w * 512);
        }
        __syncthreads();   // (compiler inserts vmcnt(0) drain before barrier)

        // K A-frags (m=key) and V B-frags (n=d), swizzled quarter reads
        bf16x8 ak[4][2], bv[4][2];
#pragma unroll
        for (int i = 0; i < 4; i++) {
            ak[i][0] = *(const bf16x8*)(Ksm[0] + (16 * i + qm) * 32 + cq);
            ak[i][1] = *(const bf16x8*)(Ksm[1] + (16 * i + qm) * 32 + cq);
        }
#pragma unroll
        for (int jd = 0; jd < 4; jd++) {
            bv[jd][0] = *(const bf16x8*)(Vsm[0] + (16 * jd + qm) * 32 + cq);
            bv[jd][1] = *(const bf16x8*)(Vsm[1] + (16 * jd + qm) * 32 + cq);
        }

        // S^T = K Q^T : lane (qm,quad) reg r holds S^T[key=16i+4quad+r][q=qm]
        f32x4 st[4];
#pragma unroll
        for (int i = 0; i < 4; i++) {
            f32x4 zz = {0.f, 0.f, 0.f, 0.f};
            zz = __builtin_amdgcn_mfma_f32_16x16x32_bf16(ak[i][0], qf0, zz, 0, 0, 0);
            zz = __builtin_amdgcn_mfma_f32_16x16x32_bf16(ak[i][1], qf1, zz, 0, 0, 0);
            st[i] = zz;
        }

        // analytic-max softmax: exponent = qk*scale*log2e - c2*key
        const int qi = bb + qm;
        const bool nomask = (kt * 64 + 63) <= bb;
        float ls = 0.f;
        unsigned pk[4][2];
#pragma unroll
        for (int i = 0; i < 4; i++) {
            float bi = -c2 * (float)(kt * 64 + 16 * i + 4 * quad);
            float p[4];
#pragma unroll
            for (int rr = 0; rr < 4; rr++) {
                float tt = st[i][rr] * 0.18033688f + (bi - c2 * (float)rr);
                float pp = __builtin_amdgcn_exp2f(tt);
                if (!nomask) {
                    int key = kt * 64 + 16 * i + 4 * quad + rr;
                    pp = (key > qi) ? 0.f : pp;
                }
                ls += pp;
                p[rr] = pp;
            }
            // pack 4 fp32 -> 4 bf16 (round-half-up + v_perm byte select)
            unsigned u0 = __builtin_bit_cast(unsigned, p[0]) + 0x8000u;
            unsigned u1 = __builtin_bit_cast(unsigned, p[1]) + 0x8000u;
            unsigned u2 = __builtin_bit_cast(unsigned, p[2]) + 0x8000u;
            unsigned u3 = __builtin_bit_cast(unsigned, p[3]) + 0x8000u;
            pk[i][0] = __builtin_amdgcn_perm(u1, u0, 0x07060302u);
            pk[i][1] = __builtin_amdgcn_perm(u3, u2, 0x07060302u);
        }
        lsum += ls;

        // P[q=qm][key=16i+4quad+{0..3}] : b64 writes, swizzled within row
#pragma unroll
        for (int i = 0; i < 4; i++) {
            uint2 pv; pv.x = pk[i][0]; pv.y = pk[i][1];
            *(uint2*)(Pb + qm * 128 + ((32 * i + 8 * quad) ^ pf)) = pv;
        }

        // O += P V : A = P rows (b128, swizzled), B = V^T rows
        bf16x8 ap0 = *(const bf16x8*)(Pb + qm * 128 + ((quad * 16) ^ pf));
        bf16x8 ap1 = *(const bf16x8*)(Pb + qm * 128 + ((64 + quad * 16) ^ pf));
#pragma unroll
        for (int jd = 0; jd < 4; jd++) {
            oacc[jd] = __builtin_amdgcn_mfma_f32_16x16x32_bf16(
                ap0, bv[jd][0], oacc[jd], 0, 0, 0);
            oacc[jd] = __builtin_amdgcn_mfma_f32_16x16x32_bf16(
                ap1, bv[jd][1], oacc[jd], 0, 0, 0);
        }

        __syncthreads();   // protect buffers before next iteration's gloads
    }

    // epilogue: reduce l across quads (lane-local rows), divide, store
    float lf = lsum;
    lf += __shfl_xor(lf, 16);
    lf += __shfl_xor(lf, 32);               // full l for q = bb+qm
#pragma unroll
    for (int rr = 0; rr < 4; rr++) {
        float lr = __shfl(lf, 4 * quad + rr);  // l for q = bb+4quad+rr
        float inv = 1.0f / lr;
        int qrow = bb + 4 * quad + rr;
#pragma unroll
        for (int jd = 0; jd < 4; jd++)
            O[base + (size_t)qrow * D_ + 16 * jd + qm] =
                f2bf(oacc[jd][rr] * inv);
    }
}

// ---------------------------------------------------------------------------
extern "C" void kernel_launch(void* const* d_in, const int* in_sizes, int n_in,
                              void* d_out, int out_size, void* d_ws, size_t ws_size,
                              hipStream_t stream) {
    (void)in_sizes; (void)n_in; (void)out_size; (void)ws_size;
    const float* x  = (const float*)d_in[0];
    const float* Wq = (const float*)d_in[1];
    const float* bq = (const float*)d_in[2];
    const float* Wk = (const float*)d_in[3];
    const float* bk = (const float*)d_in[4];
    const float* Wv = (const float*)d_in[5];
    const float* bv = (const float*)d_in[6];
    const float* Wo = (const float*)d_in[7];
    const float* bo = (const float*)d_in[8];
    float* out = (float*)d_out;

    const size_t n = (size_t)B_ * H_ * S_ * D_;  // 6291456
    // ws layout (46 MB):
    //  [0,n):   xb (dead after QKV gemm)
    //  [n,2n):  Qb -> Ob (attn reads only its own Q rows before writing them)
    //  [2n,3n): Kb
    //  [3n,4n): Vtb  (V written transposed by QKV gemm epilogue)
    //  [4n,+):  Wt, 4 x 768*768 bf16
    __bf16* xb  = (__bf16*)d_ws;
    __bf16* Qb  = xb + n;
    __bf16* Kb  = xb + 2 * n;
    __bf16* Vtb = xb + 3 * n;
    __bf16* Wt  = xb + 4 * n;
    __bf16* Ob  = Qb;

    cvt_x<<<6144, 256, 0, stream>>>(x, xb);
    wtrans<<<dim3(12, 12, 4), 256, 0, stream>>>(Wq, Wk, Wv, Wo, Wt);
    qkv_gemm<<<dim3(12, 64), 256, 0, stream>>>(
        xb, Wt, bq, bk, bv, Qb, Kb, Vtb);
    attn_k<<<1536, 256, 0, stream>>>(Qb, Kb, Vtb, Ob);
    gemm_bf<false><<<dim3(6, 64, 1), 256, 0, stream>>>(
        Ob, Wt + 3 * (size_t)E_ * E_, bo, nullptr, nullptr, out, nullptr);
}